// Round 2
// baseline (479.343 us; speedup 1.0000x reference)
//
#include <hip/hip_runtime.h>
#include <hip/hip_bf16.h>
#include <cstdint>

// Problem constants (AttnGate): B=2, S=8192, HQ=32, HK=8, D=128, GH=128, BLK=64
#define B_   2
#define S_   8192
#define HQ_  32
#define HK_  8
#define D_   128
#define GH_  128
#define NB_  128
#define G_   4
#define KQ_  512   // G_*D_ — contraction length of the Q projection

typedef _Float16 half4_t __attribute__((ext_vector_type(4)));
typedef float    f32x4   __attribute__((ext_vector_type(4)));

// ---------------------------------------------------------------------------
// Prep: wq [HK,G,D,GH] f32  ->  wqt [HK,GH,KQ] f16  (transposed so GEMM
// B-operand staging reads contiguous K)
// ---------------------------------------------------------------------------
__global__ void prep_wq(const float* __restrict__ wq, _Float16* __restrict__ wqt) {
    int idx = blockIdx.x * 256 + threadIdx.x;        // 524288 total
    int kh = idx >> 16;
    int o  = (idx >> 9) & 127;
    int i  = idx & 511;                              // i = g*D + d
    float v = wq[(size_t)(kh * 512 + i) * 128 + o];
    wqt[idx] = (_Float16)v;                          // layout [kh][o][i]
}

// ---------------------------------------------------------------------------
// K path: block pooling (mean+max over 64 keys) + wk matvec + RoPE
// -> kp_rope f32 [B,HK,NB,GH]
// ---------------------------------------------------------------------------
__global__ void kpath(const float* __restrict__ k, const float* __restrict__ wk,
                      const float* __restrict__ cosk, const float* __restrict__ sink,
                      float* __restrict__ kp_rope) {
    int bid = blockIdx.x;              // B*HK*NB = 2048
    int b  = bid >> 10;
    int kh = (bid >> 7) & 7;
    int n  = bid & 127;
    int d  = threadIdx.x;              // 128 threads, one per output dim
    __shared__ float kc[256];
    __shared__ float kpv[128];

    const float* kb = k + ((size_t)(b * S_ + n * 64) * HK_ + kh) * D_ + d;
    float sum = 0.f, mx = -INFINITY;
    #pragma unroll 8
    for (int r = 0; r < 64; ++r) {
        float v = kb[(size_t)r * (HK_ * D_)];
        sum += v; mx = fmaxf(mx, v);
    }
    kc[d]       = sum * (1.0f / 64.0f);
    kc[128 + d] = mx;
    __syncthreads();

    const float* wkb = wk + (size_t)(kh * 256) * 128 + d;   // wk[kh][i][o=d]
    float acc = 0.f;
    #pragma unroll 8
    for (int i = 0; i < 256; ++i) acc += kc[i] * wkb[(size_t)i * 128];
    kpv[d] = acc;
    __syncthreads();

    float rot = (d < 64) ? -kpv[d + 64] : kpv[d - 64];
    float c = cosk[(b * NB_ + n) * 128 + d];
    float s = sink[(b * NB_ + n) * 128 + d];
    kp_rope[((size_t)((b * 8 + kh) * 128 + n)) * 128 + d] = acc * c + rot * s;
}

// ---------------------------------------------------------------------------
// Fused: Qproj GEMM (per (b,kh): M=128-row tile, K=512, N=128) + RoPE
//        + scores GEMM (K=GH=128) + causal block mask + softmax.
// Block: 512 threads (8 waves); wave w owns s-rows w*16..w*16+15 of the tile.
// LDS (64KB): kpl [128][128]f16 swz @0 | union{ Alds[128][16]f16 + Bb swz
//             (qproj staging) , qpl [128][128]f16 swz (scores A) } @32768.
// ---------------------------------------------------------------------------
__global__ __launch_bounds__(512) void fused(
        const float* __restrict__ q, const _Float16* __restrict__ wqt,
        const float* __restrict__ cosq, const float* __restrict__ sinq,
        const float* __restrict__ kp, float* __restrict__ out) {
    int bid = blockIdx.x;              // B*HK*(S/128) = 1024
    int b  = bid >> 9;
    int kh = (bid >> 6) & 7;
    int ms = bid & 63;
    int s0 = ms * 128;
    int tid = threadIdx.x;
    int l = tid & 63, w = tid >> 6, q4 = l >> 4;

    __shared__ __align__(16) char buf[65536];
    char*     kpl  = buf;                       // [128][128] f16 swizzled
    char*     qpl  = buf + 32768;               // [128][128] f16 swizzled (post-loop)
    _Float16* Alds = (_Float16*)(buf + 32768);  // [128][16] f16      (during loop)
    char*     Bb   = buf + 36864;               // [128][16] f16 swz  (during loop)

    // ---- stage kp (f32 -> f16 swizzled); only rows that can be unmasked ----
    int ntmax16 = (((((ms << 1) | 1)) >> 4) + 1) << 4;
    const float* kpg = kp + (size_t)((b * 8 + kh) * 128) * 128;
    #pragma unroll
    for (int m = 0; m < 8; ++m) {
        int flat4 = m * 512 + tid;
        int row = flat4 >> 5;
        if (row < ntmax16) {
            int c4 = (flat4 & 31) * 4;
            f32x4 v = *(const f32x4*)(kpg + row * 128 + c4);
            half4_t h = {(_Float16)v.x, (_Float16)v.y, (_Float16)v.z, (_Float16)v.w};
            *(half4_t*)(kpl + ((row * 256 + c4 * 2) ^ ((row & 7) << 4))) = h;
        }
    }

    // ---- Q projection GEMM ----
    f32x4 acc[8];
    #pragma unroll
    for (int t = 0; t < 8; ++t)
        for (int e = 0; e < 4; ++e) acc[t][e] = 0.f;

    int ar = tid >> 2, akk = (tid & 3) * 4;          // A staging: row, k-chunk
    const float* qrow = q + (size_t)(b * S_ + s0 + ar) * (HQ_ * D_) + kh * KQ_;
    int bo = tid >> 2, bh = tid & 3;                 // B staging: col, k-chunk
    const half4_t* wrow = (const half4_t*)(wqt + (size_t)(kh * 128 + bo) * KQ_);

    f32x4   av = *(const f32x4*)(qrow + akk);        // prefetch ks=0
    half4_t bv = wrow[bh];

    for (int ks = 0; ks < 32; ++ks) {
        half4_t ah = {(_Float16)av.x, (_Float16)av.y, (_Float16)av.z, (_Float16)av.w};
        *(half4_t*)(Alds + ar * 16 + akk) = ah;
        *(half4_t*)(Bb + ((bo * 32 + bh * 8) ^ ((bo & 7) << 3))) = bv;
        __syncthreads();
        if (ks < 31) {                               // prefetch next chunk
            av = *(const f32x4*)(qrow + (ks + 1) * 16 + akk);
            bv = wrow[(ks + 1) * 4 + bh];
        }
        int arow = w * 16 + (l & 15);
        half4_t af = *(const half4_t*)(Alds + arow * 16 + q4 * 4);
        #pragma unroll
        for (int t = 0; t < 8; ++t) {
            int brow = t * 16 + (l & 15);
            half4_t bf = *(const half4_t*)(Bb + ((brow * 32 + q4 * 8) ^ ((brow & 7) << 3)));
            acc[t] = __builtin_amdgcn_mfma_f32_16x16x16f16(af, bf, acc[t], 0, 0, 0);
        }
        __syncthreads();
    }

    // ---- RoPE in registers (col+-64 = tile t+-4, same lane), write qpl f16 ----
    #pragma unroll
    for (int reg = 0; reg < 4; ++reg) {
        int srow = w * 16 + q4 * 4 + reg;
        const float* crow = cosq + (size_t)(b * S_ + s0 + srow) * GH_;
        const float* srw  = sinq + (size_t)(b * S_ + s0 + srow) * GH_;
        #pragma unroll
        for (int t = 0; t < 8; ++t) {
            int col = t * 16 + (l & 15);
            float rot = (t < 4) ? -acc[t + 4][reg] : acc[t - 4][reg];
            float v = acc[t][reg] * crow[col] + rot * srw[col];
            *(_Float16*)(qpl + ((srow * 256 + col * 2) ^ ((srow & 7) << 4))) = (_Float16)v;
        }
    }
    __syncthreads();

    // ---- scores GEMM: only block-tiles t <= thresh/16 (causal block mask) ----
    int thresh = (ms << 1) | (w >> 2);               // uniform per wave
    int nt = (thresh >> 4) + 1;
    int arow = w * 16 + (l & 15);
    half4_t af[8];
    #pragma unroll
    for (int ks = 0; ks < 8; ++ks)
        af[ks] = *(const half4_t*)(qpl + ((arow * 256 + ks * 32 + q4 * 8) ^ ((arow & 7) << 4)));
    #pragma unroll
    for (int t = 0; t < 8; ++t)
        for (int e = 0; e < 4; ++e) acc[t][e] = 0.f;
    #pragma unroll
    for (int t = 0; t < 8; ++t) {
        if (t < nt) {
            int brow = t * 16 + (l & 15);
            #pragma unroll
            for (int ks = 0; ks < 8; ++ks) {
                half4_t bf = *(const half4_t*)(kpl + ((brow * 256 + ks * 32 + q4 * 8) ^ ((brow & 7) << 4)));
                acc[t] = __builtin_amdgcn_mfma_f32_16x16x16f16(af[ks], bf, acc[t], 0, 0, 0);
            }
        }
    }

    // ---- mask + softmax (16-lane groups hold one row) + direct stores ----
    const float scale = 0.08838834764831845f;        // 1/sqrt(128)
    #pragma unroll
    for (int reg = 0; reg < 4; ++reg) {
        int srow = w * 16 + q4 * 4 + reg;
        float v[8];
        float mx = -1e30f;
        #pragma unroll
        for (int t = 0; t < 8; ++t) {
            if (t < nt) {
                int col = t * 16 + (l & 15);
                float x = acc[t][reg] * scale + ((col <= thresh) ? 0.f : -1e9f);
                v[t] = x; mx = fmaxf(mx, x);
            }
        }
        #pragma unroll
        for (int off = 1; off < 16; off <<= 1) mx = fmaxf(mx, __shfl_xor(mx, off));
        float sum = 0.f;
        #pragma unroll
        for (int t = 0; t < 8; ++t) {
            if (t < nt) { v[t] = __expf(v[t] - mx); sum += v[t]; }
        }
        #pragma unroll
        for (int off = 1; off < 16; off <<= 1) sum += __shfl_xor(sum, off);
        float r = 1.0f / sum;
        float* orow = out + (size_t)((b * 8 + kh) * S_ + s0 + srow) * NB_;
        #pragma unroll
        for (int t = 0; t < 8; ++t)
            orow[t * 16 + (l & 15)] = (t < nt) ? v[t] * r : 0.f;
    }
}

// ---------------------------------------------------------------------------
extern "C" void kernel_launch(void* const* d_in, const int* in_sizes, int n_in,
                              void* d_out, int out_size, void* d_ws, size_t ws_size,
                              hipStream_t stream) {
    const float* q    = (const float*)d_in[0];
    const float* k    = (const float*)d_in[1];
    // d_in[2] attention_mask: computed inline (causal block mask), unused
    const float* cosq = (const float*)d_in[3];
    const float* sinq = (const float*)d_in[4];
    const float* cosk = (const float*)d_in[5];
    const float* sink = (const float*)d_in[6];
    const float* wq   = (const float*)d_in[7];
    const float* wk   = (const float*)d_in[8];
    float* out = (float*)d_out;

    char* ws = (char*)d_ws;
    _Float16* wqt     = (_Float16*)ws;               // 1 MB  [HK][GH][KQ] f16
    float*    kp_rope = (float*)(ws + (1 << 20));    // 1 MB  [B][HK][NB][GH] f32

    prep_wq<<<2048, 256, 0, stream>>>(wq, wqt);
    kpath  <<<2048, 128, 0, stream>>>(k, wk, cosk, sink, kp_rope);
    fused  <<<1024, 512, 0, stream>>>(q, wqt, cosq, sinq, kp_rope, out);
}

// Round 3
// 467.561 us; speedup vs baseline: 1.0252x; 1.0252x over previous
//
#include <hip/hip_runtime.h>
#include <hip/hip_bf16.h>
#include <cstdint>

// Problem constants (AttnGate): B=2, S=8192, HQ=32, HK=8, D=128, GH=128, BLK=64
#define B_   2
#define S_   8192
#define HQ_  32
#define HK_  8
#define D_   128
#define GH_  128
#define NB_  128
#define G_   4
#define KQ_  512   // G_*D_ — contraction length of the Q projection

typedef _Float16 half4_t __attribute__((ext_vector_type(4)));
typedef _Float16 half8_t __attribute__((ext_vector_type(8)));
typedef float    f32x4   __attribute__((ext_vector_type(4)));

// ---------------------------------------------------------------------------
// Prep: wq [HK,G,D,GH] f32 -> wqt [HK,GH,KQ] f16, LDS-transposed so both the
// global read (contiguous o) and the global write (contiguous i) coalesce.
// Grid: HK*4 = 32 blocks; block = (kh, 128-wide i-chunk).
// ---------------------------------------------------------------------------
__global__ __launch_bounds__(256) void prep_wq(const float* __restrict__ wq,
                                               _Float16* __restrict__ wqt) {
    int bid = blockIdx.x;             // 32
    int kh = bid >> 2, ic = bid & 3;
    int tid = threadIdx.x;
    __shared__ _Float16 tile[128][136];   // 136*2=272B row stride, 16B-aligned

    int c4 = (tid & 31) * 4, r8 = tid >> 5;
    const float* src = wq + (size_t)(kh * 512 + ic * 128) * 128;
    #pragma unroll
    for (int j = 0; j < 16; ++j) {
        int i = j * 8 + r8;
        f32x4 v = *(const f32x4*)(src + (size_t)i * 128 + c4);
        #pragma unroll
        for (int e = 0; e < 4; ++e) tile[c4 + e][i] = (_Float16)v[e];
    }
    __syncthreads();
    int o = tid >> 1, ih = (tid & 1) * 64;
    _Float16* dst = wqt + (size_t)(kh * 128 + o) * 512 + ic * 128 + ih;
    #pragma unroll
    for (int m = 0; m < 8; ++m)
        *(half8_t*)(dst + m * 8) = *(const half8_t*)(&tile[o][ih + m * 8]);
}

// ---------------------------------------------------------------------------
// K path: block pooling (mean+max over 64 keys) + wk matvec + RoPE
// -> kp_rope f32 [B,HK,NB,GH].  256 threads, f32x4 loads (16B/lane).
// ---------------------------------------------------------------------------
__global__ __launch_bounds__(256) void kpath(
        const float* __restrict__ k, const float* __restrict__ wk,
        const float* __restrict__ cosk, const float* __restrict__ sink,
        float* __restrict__ kp_rope) {
    int bid = blockIdx.x;              // B*HK*NB = 2048
    int b  = bid >> 10;
    int kh = (bid >> 7) & 7;
    int n  = bid & 127;
    int tid = threadIdx.x;

    __shared__ f32x4 ps[8][32];
    __shared__ f32x4 pm[8][32];
    __shared__ float kc[256];
    __shared__ float pv[2][128];
    __shared__ float kpv[128];

    int c32 = tid & 31, rg = tid >> 5;
    const float* base = k + ((size_t)(b * S_ + n * 64 + rg) * HK_ + kh) * D_ + c32 * 4;
    f32x4 s4 = {0.f, 0.f, 0.f, 0.f};
    f32x4 m4 = {-1e30f, -1e30f, -1e30f, -1e30f};
    #pragma unroll
    for (int j = 0; j < 8; ++j) {
        f32x4 v = *(const f32x4*)(base + (size_t)j * 8 * (HK_ * D_));
        s4 += v;
        #pragma unroll
        for (int e = 0; e < 4; ++e) m4[e] = fmaxf(m4[e], v[e]);
    }
    ps[rg][c32] = s4; pm[rg][c32] = m4;
    __syncthreads();
    if (tid < 32) {
        f32x4 s = ps[0][tid], m = pm[0][tid];
        #pragma unroll
        for (int r = 1; r < 8; ++r) {
            s += ps[r][tid];
            #pragma unroll
            for (int e = 0; e < 4; ++e) m[e] = fmaxf(m[e], pm[r][tid][e]);
        }
        #pragma unroll
        for (int e = 0; e < 4; ++e) {
            kc[tid * 4 + e]       = s[e] * (1.0f / 64.0f);
            kc[128 + tid * 4 + e] = m[e];
        }
    }
    __syncthreads();

    int o = tid & 127, hf = tid >> 7;
    const float* wkb = wk + ((size_t)(kh * 256 + hf * 128)) * 128 + o;
    float acc = 0.f;
    #pragma unroll 8
    for (int i = 0; i < 128; ++i) acc += kc[hf * 128 + i] * wkb[(size_t)i * 128];
    pv[hf][o] = acc;
    __syncthreads();
    if (tid < 128) kpv[tid] = pv[0][tid] + pv[1][tid];
    __syncthreads();
    if (tid < 128) {
        int d = tid;
        float v = kpv[d];
        float rot = (d < 64) ? -kpv[d + 64] : kpv[d - 64];
        float c = cosk[(b * NB_ + n) * 128 + d];
        float s = sink[(b * NB_ + n) * 128 + d];
        kp_rope[((size_t)((b * 8 + kh) * 128 + n)) * 128 + d] = v * c + rot * s;
    }
}

// ---------------------------------------------------------------------------
// Fused: Qproj GEMM (M=128 tile, K=512, N=128, f16 MFMA 16x16x32, K-step 64)
//        + RoPE + scores GEMM + causal block mask + softmax.
// Block: 512 threads (8 waves); wave w owns s-rows w*16..w*16+15.
// LDS 64KB: kpl [128][256B] swz @0 | Ab [128][128B] swz @32K | Bb @48K;
//           after the GEMM loop Ab/Bb are reused as qpl [128][256B] swz.
// A/B rows are 128B -> XOR swizzle byte^((row&7)<<4) kills the 16-way conflict.
// ---------------------------------------------------------------------------
__global__ __launch_bounds__(512) void fused(
        const float* __restrict__ q, const _Float16* __restrict__ wqt,
        const float* __restrict__ cosq, const float* __restrict__ sinq,
        const float* __restrict__ kp, float* __restrict__ out) {
    int bid = blockIdx.x;              // B*HK*(S/128) = 1024
    int b  = bid >> 9;
    int kh = (bid >> 6) & 7;
    int ms = bid & 63;
    int s0 = ms * 128;
    int tid = threadIdx.x;
    int l = tid & 63, w = tid >> 6, hi = l >> 4, lo = l & 15;

    __shared__ __align__(16) char buf[65536];
    char* kpl = buf;              // [128][256B] f16 swz
    char* Ab  = buf + 32768;      // [128][128B] f16 swz (qproj A)
    char* Bb  = buf + 49152;      // [128][128B] f16 swz (qproj B)
    char* qpl = buf + 32768;      // [128][256B] f16 swz (post-loop)

    // ---- stage kp (f32 -> f16 swizzled); only rows that can be unmasked ----
    int ntmax16 = ((((ms << 1) | 1) >> 4) + 1) << 4;
    const float* kpg = kp + (size_t)((b * 8 + kh) * 128) * 128;
    #pragma unroll
    for (int m = 0; m < 8; ++m) {
        int flat4 = m * 512 + tid;
        int row = flat4 >> 5;
        if (row < ntmax16) {
            int c4 = (flat4 & 31) * 4;
            f32x4 v = *(const f32x4*)(kpg + row * 128 + c4);
            half4_t h = {(_Float16)v.x, (_Float16)v.y, (_Float16)v.z, (_Float16)v.w};
            *(half4_t*)(kpl + ((row * 256 + c4 * 2) ^ ((row & 7) << 4))) = h;
        }
    }

    // ---- Q projection GEMM: 8 K-steps of 64 ----
    f32x4 acc[8];
    #pragma unroll
    for (int t = 0; t < 8; ++t)
        for (int e = 0; e < 4; ++e) acc[t][e] = 0.f;

    int srw_ = tid >> 2;                 // staging row (both A and B): 0..127
    int sc   = (tid & 3) * 16;           // 16-element chunk within the 64-wide K-step
    const float*    qbase = q + (size_t)(b * S_ + s0 + srw_) * (HQ_ * D_) + kh * KQ_ + sc;
    const _Float16* wbase = wqt + (size_t)(kh * 128 + srw_) * KQ_ + sc;
    int aoff0 = (srw_ * 128 + sc * 2) ^ ((srw_ & 7) << 4);
    int aoff1 = (srw_ * 128 + sc * 2 + 16) ^ ((srw_ & 7) << 4);

    f32x4 av[4]; half8_t bv0, bv1;
    #pragma unroll
    for (int j = 0; j < 4; ++j) av[j] = *(const f32x4*)(qbase + j * 4);
    bv0 = *(const half8_t*)(wbase);
    bv1 = *(const half8_t*)(wbase + 8);

    for (int ks = 0; ks < 8; ++ks) {
        half8_t ah0, ah1;
        #pragma unroll
        for (int e = 0; e < 4; ++e) {
            ah0[e] = (_Float16)av[0][e]; ah0[4 + e] = (_Float16)av[1][e];
            ah1[e] = (_Float16)av[2][e]; ah1[4 + e] = (_Float16)av[3][e];
        }
        *(half8_t*)(Ab + aoff0) = ah0;
        *(half8_t*)(Ab + aoff1) = ah1;
        *(half8_t*)(Bb + aoff0) = bv0;
        *(half8_t*)(Bb + aoff1) = bv1;
        if (ks < 7) {                    // prefetch next K-chunk (in flight over MFMA)
            #pragma unroll
            for (int j = 0; j < 4; ++j)
                av[j] = *(const f32x4*)(qbase + (ks + 1) * 64 + j * 4);
            bv0 = *(const half8_t*)(wbase + (ks + 1) * 64);
            bv1 = *(const half8_t*)(wbase + (ks + 1) * 64 + 8);
        }
        __syncthreads();
        int arow = w * 16 + lo;
        #pragma unroll
        for (int sl = 0; sl < 2; ++sl) {
            half8_t af = *(const half8_t*)(Ab + ((arow * 128 + sl * 64 + hi * 16) ^ ((arow & 7) << 4)));
            #pragma unroll
            for (int t = 0; t < 8; ++t) {
                int br = t * 16 + lo;
                half8_t bf = *(const half8_t*)(Bb + ((br * 128 + sl * 64 + hi * 16) ^ ((br & 7) << 4)));
                acc[t] = __builtin_amdgcn_mfma_f32_16x16x32_f16(af, bf, acc[t], 0, 0, 0);
            }
        }
        __syncthreads();
    }

    // ---- RoPE in registers (col+-64 = tile t+-4, same lane) -> qpl f16 swz ----
    #pragma unroll
    for (int reg = 0; reg < 4; ++reg) {
        int srow = w * 16 + hi * 4 + reg;
        const float* crow = cosq + (size_t)(b * S_ + s0 + srow) * GH_;
        const float* srw  = sinq + (size_t)(b * S_ + s0 + srow) * GH_;
        #pragma unroll
        for (int t = 0; t < 8; ++t) {
            int col = t * 16 + lo;
            float rot = (t < 4) ? -acc[t + 4][reg] : acc[t - 4][reg];
            float v = acc[t][reg] * crow[col] + rot * srw[col];
            *(_Float16*)(qpl + ((srow * 256 + col * 2) ^ ((srow & 7) << 4))) = (_Float16)v;
        }
    }
    __syncthreads();

    // ---- scores GEMM: only block-tiles t < nt (causal block mask) ----
    int thresh = (ms << 1) | (w >> 2);   // uniform per wave: s//64 for this row group
    int nt = (thresh >> 4) + 1;
    int arow = w * 16 + lo;
    half8_t qf[4];
    #pragma unroll
    for (int sl = 0; sl < 4; ++sl)
        qf[sl] = *(const half8_t*)(qpl + ((arow * 256 + sl * 64 + hi * 16) ^ ((arow & 7) << 4)));
    #pragma unroll
    for (int t = 0; t < 8; ++t)
        for (int e = 0; e < 4; ++e) acc[t][e] = 0.f;
    #pragma unroll
    for (int t = 0; t < 8; ++t) {
        if (t < nt) {
            int br = t * 16 + lo;
            #pragma unroll
            for (int sl = 0; sl < 4; ++sl) {
                half8_t bf = *(const half8_t*)(kpl + ((br * 256 + sl * 64 + hi * 16) ^ ((br & 7) << 4)));
                acc[t] = __builtin_amdgcn_mfma_f32_16x16x32_f16(qf[sl], bf, acc[t], 0, 0, 0);
            }
        }
    }

    // ---- mask + softmax (16-lane groups hold one row) + direct stores ----
    const float scale = 0.08838834764831845f;        // 1/sqrt(128)
    #pragma unroll
    for (int reg = 0; reg < 4; ++reg) {
        int srow = w * 16 + hi * 4 + reg;
        float v[8];
        float mx = -1e30f;
        #pragma unroll
        for (int t = 0; t < 8; ++t) {
            if (t < nt) {
                int col = t * 16 + lo;
                float x = acc[t][reg] * scale + ((col <= thresh) ? 0.f : -1e9f);
                v[t] = x; mx = fmaxf(mx, x);
            }
        }
        #pragma unroll
        for (int off = 1; off < 16; off <<= 1) mx = fmaxf(mx, __shfl_xor(mx, off));
        float sum = 0.f;
        #pragma unroll
        for (int t = 0; t < 8; ++t) {
            if (t < nt) { v[t] = __expf(v[t] - mx); sum += v[t]; }
        }
        #pragma unroll
        for (int off = 1; off < 16; off <<= 1) sum += __shfl_xor(sum, off);
        float r = 1.0f / sum;
        float* orow = out + (size_t)((b * 8 + kh) * S_ + s0 + srow) * NB_;
        #pragma unroll
        for (int t = 0; t < 8; ++t)
            orow[t * 16 + lo] = (t < nt) ? v[t] * r : 0.f;
    }
}

// ---------------------------------------------------------------------------
extern "C" void kernel_launch(void* const* d_in, const int* in_sizes, int n_in,
                              void* d_out, int out_size, void* d_ws, size_t ws_size,
                              hipStream_t stream) {
    const float* q    = (const float*)d_in[0];
    const float* k    = (const float*)d_in[1];
    // d_in[2] attention_mask: computed inline (causal block mask), unused
    const float* cosq = (const float*)d_in[3];
    const float* sinq = (const float*)d_in[4];
    const float* cosk = (const float*)d_in[5];
    const float* sink = (const float*)d_in[6];
    const float* wq   = (const float*)d_in[7];
    const float* wk   = (const float*)d_in[8];
    float* out = (float*)d_out;

    char* ws = (char*)d_ws;
    _Float16* wqt     = (_Float16*)ws;               // 1 MB   [HK][GH][KQ] f16
    float*    kp_rope = (float*)(ws + (1 << 20));    // 512 KB [B][HK][NB][GH] f32

    prep_wq<<<32,   256, 0, stream>>>(wq, wqt);
    kpath  <<<2048, 256, 0, stream>>>(k, wk, cosk, sink, kp_rope);
    fused  <<<1024, 512, 0, stream>>>(q, wqt, cosq, sinq, kp_rope, out);
}